// Round 5
// baseline (656.707 us; speedup 1.0000x reference)
//
#include <hip/hip_runtime.h>
#include <math.h>

// ---------------------------------------------------------------------------
// GCN 3-layer forward, fp32.
//  per layer: Ys = dinv .* (H @ W) ;  out_i = dinv_i*( Ys_i + sum_e Ys[src_e] )
//                                             / deg_i + b
// CSR-by-dst built on device each call; segments padded to multiples of 8,
// holes point at zero-row index n (Ys has n+1 rows, row n = 0).
// R2: LDS-tiled register-blocked GEMM (no spills).
// R4: shfl-free aggregation — dinv folded into Y at GEMM epilogue, padded CSR.
// R5: deep-MLP aggregation — first 16 (agg128) / 32 (agg64) edge-row loads
//     issued into register temps before any adds (discriminates MSHR-bound
//     vs fabric-floor); prep kernels fused.
// ---------------------------------------------------------------------------

#define BLK 256

// init deg=1, fill=0, and colidx=zero-row over padded length (grid-stride)
__global__ void init_and_pad(int* __restrict__ deg, int* __restrict__ fill, int n,
                             int* __restrict__ colidx, int val, int len) {
    int i = blockIdx.x * blockDim.x + threadIdx.x;
    int stride = gridDim.x * blockDim.x;
    for (; i < len; i += stride) {
        if (i < n) { deg[i] = 1; fill[i] = 0; }
        colidx[i] = val;
    }
}

__global__ void count_deg(const int* __restrict__ dst, int* __restrict__ deg, int E) {
    int e = blockIdx.x * blockDim.x + threadIdx.x;
    if (e < E) atomicAdd(&deg[dst[e]], 1);
}

// padded per-node edge capacity: roundup8(deg-1)
__device__ __forceinline__ int padcap(int d) { return (d - 1 + 7) & ~7; }

// ---- exclusive scan of padcap(deg) into rowptr, 3 passes ----
__global__ void scan_block_sums(const int* __restrict__ deg, int* __restrict__ bsum, int n) {
    __shared__ int s[BLK];
    int i = blockIdx.x * BLK + threadIdx.x;
    s[threadIdx.x] = (i < n) ? padcap(deg[i]) : 0;
    __syncthreads();
    for (int off = BLK / 2; off > 0; off >>= 1) {
        if (threadIdx.x < off) s[threadIdx.x] += s[threadIdx.x + off];
        __syncthreads();
    }
    if (threadIdx.x == 0) bsum[blockIdx.x] = s[0];
}

__global__ void scan_partials_excl(int* __restrict__ bsum, int nb) {
    __shared__ int a[512];
    __shared__ int b[512];
    int t = threadIdx.x;
    int v = (t < nb) ? bsum[t] : 0;
    a[t] = v;
    __syncthreads();
    int* s = a; int* d = b;
    for (int off = 1; off < 512; off <<= 1) {
        int val = s[t];
        if (t >= off) val += s[t - off];
        d[t] = val;
        __syncthreads();
        int* tmp = s; s = d; d = tmp;
    }
    if (t < nb) bsum[t] = s[t] - v;   // exclusive
}

__global__ void scan_write_rowptr(const int* __restrict__ deg, const int* __restrict__ bsum,
                                  int* __restrict__ rowptr, float* __restrict__ dinv, int n) {
    __shared__ int a[BLK];
    __shared__ int b[BLK];
    int t = threadIdx.x;
    int i = blockIdx.x * BLK + t;
    int dgv = (i < n) ? deg[i] : 1;
    int v = (i < n) ? padcap(dgv) : 0;
    a[t] = v;
    __syncthreads();
    int* s = a; int* d = b;
    for (int off = 1; off < BLK; off <<= 1) {
        int val = s[t];
        if (t >= off) val += s[t - off];
        d[t] = val;
        __syncthreads();
        int* tmp = s; s = d; d = tmp;
    }
    if (i < n) {
        rowptr[i] = (s[t] - v) + bsum[blockIdx.x];
        dinv[i] = 1.0f / sqrtf((float)dgv);
    }
}

__global__ void place_edges(const int* __restrict__ src, const int* __restrict__ dst,
                            const int* __restrict__ rowptr, int* __restrict__ fill,
                            int* __restrict__ colidx, int E) {
    int e = blockIdx.x * blockDim.x + threadIdx.x;
    if (e < E) {
        int d = dst[e];
        int pos = rowptr[d] + atomicAdd(&fill[d], 1);
        colidx[pos] = src[e];
    }
}

// ---- GEMM: Ys[n+1,KOUT]; rows<n: dinv[row]*(H@W); row n: zeros ----
template <int KOUT>
__global__ __launch_bounds__(256) void gemm_tiled(const float* __restrict__ H,
                                                  const float* __restrict__ W,
                                                  const float* __restrict__ dinv,
                                                  float* __restrict__ Y, int n) {
    constexpr int ROWS = (KOUT == 128) ? 64 : 128;
    constexpr int HSTR = 36;  // padded k-stride: float4 aligned, conflict-free reads
    __shared__ float Hl[ROWS][HSTR];   // [row][kk]
    __shared__ float Wl[32][KOUT];     // [kk][c]

    const int t = threadIdx.x;
    const int wave = t >> 6, lane = t & 63;
    const int rg = lane >> 3;          // 0..7 row group
    const int cg = lane & 7;           // 0..7 col group
    const int rpanel = (KOUT == 128) ? (wave >> 1) : wave;
    const int cpanel = (KOUT == 128) ? (wave & 1) : 0;
    const int row0 = blockIdx.x * ROWS;
    const int cbase = cpanel * 64 + cg * 8;

    if (blockIdx.x == 0 && t < KOUT) Y[(size_t)n * KOUT + t] = 0.f;  // zero pad-row

    float acc[4][8];
#pragma unroll
    for (int i = 0; i < 4; i++)
#pragma unroll
        for (int j = 0; j < 8; j++) acc[i][j] = 0.f;

    for (int kt = 0; kt < 128; kt += 32) {
        // stage H tile: ROWS x 32 (8 threads/row, float4 each; coalesced 128B/row)
#pragma unroll
        for (int s = 0; s < ROWS / 32; s++) {
            int r = s * 32 + (t >> 3);
            int kk = (t & 7) * 4;
            int row = row0 + r;
            float4 v = make_float4(0.f, 0.f, 0.f, 0.f);
            if (row < n) v = *(const float4*)(H + (size_t)row * 128 + kt + kk);
            Hl[r][kk] = v.x; Hl[r][kk + 1] = v.y; Hl[r][kk + 2] = v.z; Hl[r][kk + 3] = v.w;
        }
        // stage W tile: 32 x KOUT, contiguous chunk
        {
            const float* Wg = W + (size_t)kt * KOUT;
            float* Wf = &Wl[0][0];
            for (int idx = t * 4; idx < 32 * KOUT; idx += 1024) {
                *(float4*)(Wf + idx) = *(const float4*)(Wg + idx);
            }
        }
        __syncthreads();

#pragma unroll 2
        for (int kk = 0; kk < 32; kk += 4) {
            float4 a[4];
#pragma unroll
            for (int i = 0; i < 4; i++)
                a[i] = *(const float4*)(&Hl[rpanel * 32 + rg + 8 * i][kk]);
#pragma unroll
            for (int q = 0; q < 4; q++) {
                float4 w0 = *(const float4*)(&Wl[kk + q][cbase]);
                float4 w1 = *(const float4*)(&Wl[kk + q][cbase + 4]);
#pragma unroll
                for (int i = 0; i < 4; i++) {
                    float av = (q == 0) ? a[i].x : (q == 1) ? a[i].y : (q == 2) ? a[i].z : a[i].w;
                    acc[i][0] += av * w0.x; acc[i][1] += av * w0.y;
                    acc[i][2] += av * w0.z; acc[i][3] += av * w0.w;
                    acc[i][4] += av * w1.x; acc[i][5] += av * w1.y;
                    acc[i][6] += av * w1.z; acc[i][7] += av * w1.w;
                }
            }
        }
        __syncthreads();
    }

#pragma unroll
    for (int i = 0; i < 4; i++) {
        int row = row0 + rpanel * 32 + rg + 8 * i;
        if (row < n) {
            float dv = dinv[row];
            float* yp = Y + (size_t)row * KOUT + cbase;
            *(float4*)yp = make_float4(dv * acc[i][0], dv * acc[i][1], dv * acc[i][2], dv * acc[i][3]);
            *(float4*)(yp + 4) = make_float4(dv * acc[i][4], dv * acc[i][5], dv * acc[i][6], dv * acc[i][7]);
        }
    }
}

// ---- aggregation KOUT=128: wave/node, lane-halves own full rows.
// Deep-MLP: first 16 edge-row loads issued into temps before any adds. ----
template <bool RELU>
__global__ __launch_bounds__(256) void agg128(const float* __restrict__ Ys,
                                              const int* __restrict__ rowptr,
                                              const int* __restrict__ deg,
                                              const float* __restrict__ dinv,
                                              const int* __restrict__ colidx,
                                              const float* __restrict__ bias,
                                              float* __restrict__ out, int n) {
    int wid = (blockIdx.x * blockDim.x + threadIdx.x) >> 6;
    int lane = threadIdx.x & 63;
    if (wid >= n) return;
    const int half = lane >> 5;
    const int l5 = lane & 31;

    int start = __builtin_amdgcn_readfirstlane(rowptr[wid]);
    int dg    = __builtin_amdgcn_readfirstlane(deg[wid]);
    int mpad  = padcap(dg);
    float di = dinv[wid];

    float4 acc = make_float4(0.f, 0.f, 0.f, 0.f);
    if (half == 0) {   // self term (Ys already includes dinv_i)
        acc = *(const float4*)(Ys + ((size_t)wid << 7) + l5 * 4);
    }

    const int4* cp4 = (const int4*)(colidx + start);   // start % 8 == 0 -> aligned
    if (mpad > 0) {
        // meta for first 16 edges (beyond-segment guarded -> zero row)
        int4 a = cp4[0], b = cp4[1];
        int4 c, d;
        if (mpad > 8) { c = cp4[2]; d = cp4[3]; }
        else { c = make_int4(n, n, n, n); d = c; }

        int idx[8];
        idx[0] = half ? a.y : a.x; idx[1] = half ? a.w : a.z;
        idx[2] = half ? b.y : b.x; idx[3] = half ? b.w : b.z;
        idx[4] = half ? c.y : c.x; idx[5] = half ? c.w : c.z;
        idx[6] = half ? d.y : d.x; idx[7] = half ? d.w : d.z;
        float4 r[8];
#pragma unroll
        for (int k = 0; k < 8; k++)
            r[k] = *(const float4*)(Ys + ((size_t)idx[k] << 7) + l5 * 4);
#pragma unroll
        for (int k = 0; k < 8; k++) {
            acc.x += r[k].x; acc.y += r[k].y; acc.z += r[k].z; acc.w += r[k].w;
        }

        for (int j = 16; j < mpad; j += 8) {
            int4 e = cp4[j >> 2], f = cp4[(j >> 2) + 1];
            int i0 = half ? e.y : e.x, i1 = half ? e.w : e.z;
            int i2 = half ? f.y : f.x, i3 = half ? f.w : f.z;
            float4 s0 = *(const float4*)(Ys + ((size_t)i0 << 7) + l5 * 4);
            float4 s1 = *(const float4*)(Ys + ((size_t)i1 << 7) + l5 * 4);
            float4 s2 = *(const float4*)(Ys + ((size_t)i2 << 7) + l5 * 4);
            float4 s3 = *(const float4*)(Ys + ((size_t)i3 << 7) + l5 * 4);
            acc.x += s0.x + s1.x + s2.x + s3.x;
            acc.y += s0.y + s1.y + s2.y + s3.y;
            acc.z += s0.z + s1.z + s2.z + s3.z;
            acc.w += s0.w + s1.w + s2.w + s3.w;
        }
    }
    // combine halves
    acc.x += __shfl_xor(acc.x, 32);
    acc.y += __shfl_xor(acc.y, 32);
    acc.z += __shfl_xor(acc.z, 32);
    acc.w += __shfl_xor(acc.w, 32);

    if (half == 0) {
        float scale = di / (float)dg;
        float4 bv = *(const float4*)(bias + l5 * 4);
        float4 o;
        o.x = acc.x * scale + bv.x;
        o.y = acc.y * scale + bv.y;
        o.z = acc.z * scale + bv.z;
        o.w = acc.w * scale + bv.w;
        if (RELU) {
            o.x = fmaxf(o.x, 0.f); o.y = fmaxf(o.y, 0.f);
            o.z = fmaxf(o.z, 0.f); o.w = fmaxf(o.w, 0.f);
        }
        *(float4*)(out + ((size_t)wid << 7) + l5 * 4) = o;
    }
}

// ---- aggregation KOUT=64: lane-quarters own rows; first 32 edges deep. ----
template <bool RELU>
__global__ __launch_bounds__(256) void agg64(const float* __restrict__ Ys,
                                             const int* __restrict__ rowptr,
                                             const int* __restrict__ deg,
                                             const float* __restrict__ dinv,
                                             const int* __restrict__ colidx,
                                             const float* __restrict__ bias,
                                             float* __restrict__ out, int n) {
    int wid = (blockIdx.x * blockDim.x + threadIdx.x) >> 6;
    int lane = threadIdx.x & 63;
    if (wid >= n) return;
    const int q = lane >> 4;
    const int l4 = lane & 15;

    int start = __builtin_amdgcn_readfirstlane(rowptr[wid]);
    int dg    = __builtin_amdgcn_readfirstlane(deg[wid]);
    int mpad  = padcap(dg);
    float di = dinv[wid];

    float4 acc = make_float4(0.f, 0.f, 0.f, 0.f);
    if (q == 0) {
        acc = *(const float4*)(Ys + ((size_t)wid << 6) + l4 * 4);
    }

    const int4* cp4 = (const int4*)(colidx + start);
    if (mpad > 0) {
        int4 m[8];
        m[0] = cp4[0]; m[1] = cp4[1];
        if (mpad > 8)  { m[2] = cp4[2]; m[3] = cp4[3]; }
        else           { m[2] = make_int4(n, n, n, n); m[3] = m[2]; }
        if (mpad > 16) { m[4] = cp4[4]; m[5] = cp4[5]; }
        else           { m[4] = make_int4(n, n, n, n); m[5] = m[4]; }
        if (mpad > 24) { m[6] = cp4[6]; m[7] = cp4[7]; }
        else           { m[6] = make_int4(n, n, n, n); m[7] = m[6]; }

        float4 r[8];
#pragma unroll
        for (int k = 0; k < 8; k++) {
            int se = (q == 0) ? m[k].x : (q == 1) ? m[k].y : (q == 2) ? m[k].z : m[k].w;
            r[k] = *(const float4*)(Ys + ((size_t)se << 6) + l4 * 4);
        }
#pragma unroll
        for (int k = 0; k < 8; k++) {
            acc.x += r[k].x; acc.y += r[k].y; acc.z += r[k].z; acc.w += r[k].w;
        }

        for (int j = 32; j < mpad; j += 8) {
            int4 e = cp4[j >> 2], f = cp4[(j >> 2) + 1];
            int i0 = (q == 0) ? e.x : (q == 1) ? e.y : (q == 2) ? e.z : e.w;
            int i1 = (q == 0) ? f.x : (q == 1) ? f.y : (q == 2) ? f.z : f.w;
            float4 s0 = *(const float4*)(Ys + ((size_t)i0 << 6) + l4 * 4);
            float4 s1 = *(const float4*)(Ys + ((size_t)i1 << 6) + l4 * 4);
            acc.x += s0.x + s1.x;
            acc.y += s0.y + s1.y;
            acc.z += s0.z + s1.z;
            acc.w += s0.w + s1.w;
        }
    }
    // combine quarters
    acc.x += __shfl_xor(acc.x, 16); acc.x += __shfl_xor(acc.x, 32);
    acc.y += __shfl_xor(acc.y, 16); acc.y += __shfl_xor(acc.y, 32);
    acc.z += __shfl_xor(acc.z, 16); acc.z += __shfl_xor(acc.z, 32);
    acc.w += __shfl_xor(acc.w, 16); acc.w += __shfl_xor(acc.w, 32);

    if (q == 0) {
        float scale = di / (float)dg;
        float4 bv = *(const float4*)(bias + l4 * 4);
        float4 o;
        o.x = acc.x * scale + bv.x;
        o.y = acc.y * scale + bv.y;
        o.z = acc.z * scale + bv.z;
        o.w = acc.w * scale + bv.w;
        if (RELU) {
            o.x = fmaxf(o.x, 0.f); o.y = fmaxf(o.y, 0.f);
            o.z = fmaxf(o.z, 0.f); o.w = fmaxf(o.w, 0.f);
        }
        *(float4*)(out + ((size_t)wid << 6) + l4 * 4) = o;
    }
}

extern "C" void kernel_launch(void* const* d_in, const int* in_sizes, int n_in,
                              void* d_out, int out_size, void* d_ws, size_t ws_size,
                              hipStream_t stream) {
    const float* x  = (const float*)d_in[0];
    const int*   ei = (const int*)d_in[1];
    const float* W1 = (const float*)d_in[2];
    const float* b1 = (const float*)d_in[3];
    const float* W2 = (const float*)d_in[4];
    const float* b2 = (const float*)d_in[5];
    const float* W3 = (const float*)d_in[6];
    const float* b3 = (const float*)d_in[7];
    float* out = (float*)d_out;

    const int n = in_sizes[0] / 128;      // 100000
    const int E = in_sizes[1] / 2;        // 1600000
    const int* srcA = ei;
    const int* dstA = ei + E;
    const int Epad = E + 8 * n + 64;      // CSR padded to 8 per node + slack

    // ---- workspace carve (aligned to 256B) ----
    auto alignup = [](size_t v) { return (v + 255) & ~(size_t)255; };
    char* base = (char*)d_ws;
    size_t off = 0;
    int* deg    = (int*)(base + off); off = alignup(off + (size_t)n * 4);
    int* fill   = (int*)(base + off); off = alignup(off + (size_t)n * 4);
    int* rowptr = (int*)(base + off); off = alignup(off + (size_t)n * 4);
    int* bsum   = (int*)(base + off); off = alignup(off + (size_t)1024 * 4);
    int* colidx = (int*)(base + off); off = alignup(off + (size_t)Epad * 4);
    float* dinv = (float*)(base + off); off = alignup(off + (size_t)n * 4);
    float* Hb   = (float*)(base + off); off = alignup(off + (size_t)n * 128 * 4);
    float* Yb   = (float*)(base + off); off = alignup(off + (size_t)(n + 1) * 128 * 4);
    (void)ws_size;

    const int nbN = (n + BLK - 1) / BLK;      // 391
    const int nbE = (E + BLK - 1) / BLK;

    // ---- prep: degrees, dinv, padded CSR (holes -> zero-row index n) ----
    init_and_pad<<<2048, BLK, 0, stream>>>(deg, fill, n, colidx, n, Epad);
    count_deg<<<nbE, BLK, 0, stream>>>(dstA, deg, E);
    scan_block_sums<<<nbN, BLK, 0, stream>>>(deg, bsum, n);
    scan_partials_excl<<<1, 512, 0, stream>>>(bsum, nbN);
    scan_write_rowptr<<<nbN, BLK, 0, stream>>>(deg, bsum, rowptr, dinv, n);
    place_edges<<<nbE, BLK, 0, stream>>>(srcA, dstA, rowptr, fill, colidx, E);

    const int aggBlocks = (n * 64 + BLK - 1) / BLK;   // wave per node

    // ---- layer 1: x @ W1 -> agg -> relu -> Hb ----
    gemm_tiled<128><<<(n + 63) / 64, 256, 0, stream>>>(x, W1, dinv, Yb, n);
    agg128<true><<<aggBlocks, BLK, 0, stream>>>(Yb, rowptr, deg, dinv, colidx, b1, Hb, n);

    // ---- layer 2 ----
    gemm_tiled<128><<<(n + 63) / 64, 256, 0, stream>>>(Hb, W2, dinv, Yb, n);
    agg128<true><<<aggBlocks, BLK, 0, stream>>>(Yb, rowptr, deg, dinv, colidx, b2, Hb, n);

    // ---- layer 3 (out dim 64, no relu) ----
    gemm_tiled<64><<<(n + 127) / 128, 256, 0, stream>>>(Hb, W3, dinv, Yb, n);
    agg64<false><<<aggBlocks, BLK, 0, stream>>>(Yb, rowptr, deg, dinv, colidx, b3, out, n);
}

// Round 6
// 490.178 us; speedup vs baseline: 1.3397x; 1.3397x over previous
//
#include <hip/hip_runtime.h>
#include <hip/hip_fp16.h>
#include <math.h>

// ---------------------------------------------------------------------------
// GCN 3-layer forward, fp32 compute, fp16 gather payload.
//  per layer: Ys = fp16( dinv .* (H @ W) ) ;  out_i = dinv_i*( Ys_i +
//             sum_e Ys[src_e] ) / deg_i + b   (accumulated in fp32)
// CSR-by-dst built on device each call; segments padded to multiples of 8,
// holes point at zero-row index n (Ys has n+1 rows, row n = 0).
// R2: LDS-tiled register-blocked GEMM (no spills).
// R4: shfl-free aggregation, dinv folded into Y at GEMM epilogue, padded CSR.
// R5 lesson: deep temp arrays spill (agg64 66->127us, 300MB scratch) — revert.
// R6: Y stored fp16 — halves the structural 8-XCD x |Y| L2-refill traffic
//     (406MB -> ~210MB); fp32 accumulation keeps error ~1e-3 rel (budget 2%).
// ---------------------------------------------------------------------------

#define BLK 256

// init deg=1, fill=0, and colidx=zero-row over padded length (grid-stride)
__global__ void init_and_pad(int* __restrict__ deg, int* __restrict__ fill, int n,
                             int* __restrict__ colidx, int val, int len) {
    int i = blockIdx.x * blockDim.x + threadIdx.x;
    int stride = gridDim.x * blockDim.x;
    for (; i < len; i += stride) {
        if (i < n) { deg[i] = 1; fill[i] = 0; }
        colidx[i] = val;
    }
}

__global__ void count_deg(const int* __restrict__ dst, int* __restrict__ deg, int E) {
    int e = blockIdx.x * blockDim.x + threadIdx.x;
    if (e < E) atomicAdd(&deg[dst[e]], 1);
}

// padded per-node edge capacity: roundup8(deg-1)
__device__ __forceinline__ int padcap(int d) { return (d - 1 + 7) & ~7; }

// ---- exclusive scan of padcap(deg) into rowptr, 3 passes ----
__global__ void scan_block_sums(const int* __restrict__ deg, int* __restrict__ bsum, int n) {
    __shared__ int s[BLK];
    int i = blockIdx.x * BLK + threadIdx.x;
    s[threadIdx.x] = (i < n) ? padcap(deg[i]) : 0;
    __syncthreads();
    for (int off = BLK / 2; off > 0; off >>= 1) {
        if (threadIdx.x < off) s[threadIdx.x] += s[threadIdx.x + off];
        __syncthreads();
    }
    if (threadIdx.x == 0) bsum[blockIdx.x] = s[0];
}

__global__ void scan_partials_excl(int* __restrict__ bsum, int nb) {
    __shared__ int a[512];
    __shared__ int b[512];
    int t = threadIdx.x;
    int v = (t < nb) ? bsum[t] : 0;
    a[t] = v;
    __syncthreads();
    int* s = a; int* d = b;
    for (int off = 1; off < 512; off <<= 1) {
        int val = s[t];
        if (t >= off) val += s[t - off];
        d[t] = val;
        __syncthreads();
        int* tmp = s; s = d; d = tmp;
    }
    if (t < nb) bsum[t] = s[t] - v;   // exclusive
}

__global__ void scan_write_rowptr(const int* __restrict__ deg, const int* __restrict__ bsum,
                                  int* __restrict__ rowptr, float* __restrict__ dinv, int n) {
    __shared__ int a[BLK];
    __shared__ int b[BLK];
    int t = threadIdx.x;
    int i = blockIdx.x * BLK + t;
    int dgv = (i < n) ? deg[i] : 1;
    int v = (i < n) ? padcap(dgv) : 0;
    a[t] = v;
    __syncthreads();
    int* s = a; int* d = b;
    for (int off = 1; off < BLK; off <<= 1) {
        int val = s[t];
        if (t >= off) val += s[t - off];
        d[t] = val;
        __syncthreads();
        int* tmp = s; s = d; d = tmp;
    }
    if (i < n) {
        rowptr[i] = (s[t] - v) + bsum[blockIdx.x];
        dinv[i] = 1.0f / sqrtf((float)dgv);
    }
}

__global__ void place_edges(const int* __restrict__ src, const int* __restrict__ dst,
                            const int* __restrict__ rowptr, int* __restrict__ fill,
                            int* __restrict__ colidx, int E) {
    int e = blockIdx.x * blockDim.x + threadIdx.x;
    if (e < E) {
        int d = dst[e];
        int pos = rowptr[d] + atomicAdd(&fill[d], 1);
        colidx[pos] = src[e];
    }
}

// ---- GEMM: Ys[n+1,KOUT] fp16; rows<n: fp16(dinv[row]*(H@W)); row n: zeros ----
template <int KOUT>
__global__ __launch_bounds__(256) void gemm_tiled(const float* __restrict__ H,
                                                  const float* __restrict__ W,
                                                  const float* __restrict__ dinv,
                                                  __half* __restrict__ Y, int n) {
    constexpr int ROWS = (KOUT == 128) ? 64 : 128;
    constexpr int HSTR = 36;  // padded k-stride: float4 aligned, conflict-free reads
    __shared__ float Hl[ROWS][HSTR];   // [row][kk]
    __shared__ float Wl[32][KOUT];     // [kk][c]

    const int t = threadIdx.x;
    const int wave = t >> 6, lane = t & 63;
    const int rg = lane >> 3;          // 0..7 row group
    const int cg = lane & 7;           // 0..7 col group
    const int rpanel = (KOUT == 128) ? (wave >> 1) : wave;
    const int cpanel = (KOUT == 128) ? (wave & 1) : 0;
    const int row0 = blockIdx.x * ROWS;
    const int cbase = cpanel * 64 + cg * 8;

    if (blockIdx.x == 0 && t < KOUT) Y[(size_t)n * KOUT + t] = __float2half(0.f);

    float acc[4][8];
#pragma unroll
    for (int i = 0; i < 4; i++)
#pragma unroll
        for (int j = 0; j < 8; j++) acc[i][j] = 0.f;

    for (int kt = 0; kt < 128; kt += 32) {
        // stage H tile: ROWS x 32 (8 threads/row, float4 each; coalesced 128B/row)
#pragma unroll
        for (int s = 0; s < ROWS / 32; s++) {
            int r = s * 32 + (t >> 3);
            int kk = (t & 7) * 4;
            int row = row0 + r;
            float4 v = make_float4(0.f, 0.f, 0.f, 0.f);
            if (row < n) v = *(const float4*)(H + (size_t)row * 128 + kt + kk);
            Hl[r][kk] = v.x; Hl[r][kk + 1] = v.y; Hl[r][kk + 2] = v.z; Hl[r][kk + 3] = v.w;
        }
        // stage W tile: 32 x KOUT, contiguous chunk
        {
            const float* Wg = W + (size_t)kt * KOUT;
            float* Wf = &Wl[0][0];
            for (int idx = t * 4; idx < 32 * KOUT; idx += 1024) {
                *(float4*)(Wf + idx) = *(const float4*)(Wg + idx);
            }
        }
        __syncthreads();

#pragma unroll 2
        for (int kk = 0; kk < 32; kk += 4) {
            float4 a[4];
#pragma unroll
            for (int i = 0; i < 4; i++)
                a[i] = *(const float4*)(&Hl[rpanel * 32 + rg + 8 * i][kk]);
#pragma unroll
            for (int q = 0; q < 4; q++) {
                float4 w0 = *(const float4*)(&Wl[kk + q][cbase]);
                float4 w1 = *(const float4*)(&Wl[kk + q][cbase + 4]);
#pragma unroll
                for (int i = 0; i < 4; i++) {
                    float av = (q == 0) ? a[i].x : (q == 1) ? a[i].y : (q == 2) ? a[i].z : a[i].w;
                    acc[i][0] += av * w0.x; acc[i][1] += av * w0.y;
                    acc[i][2] += av * w0.z; acc[i][3] += av * w0.w;
                    acc[i][4] += av * w1.x; acc[i][5] += av * w1.y;
                    acc[i][6] += av * w1.z; acc[i][7] += av * w1.w;
                }
            }
        }
        __syncthreads();
    }

#pragma unroll
    for (int i = 0; i < 4; i++) {
        int row = row0 + rpanel * 32 + rg + 8 * i;
        if (row < n) {
            float dv = dinv[row];
            __half hv[8];
#pragma unroll
            for (int j = 0; j < 8; j++) hv[j] = __float2half_rn(dv * acc[i][j]);
            *(uint4*)(Y + (size_t)row * KOUT + cbase) = *(const uint4*)hv;
        }
    }
}

__device__ __forceinline__ int sel4(const int4 v, int q) {
    return (q == 0) ? v.x : (q == 1) ? v.y : (q == 2) ? v.z : v.w;
}

__device__ __forceinline__ void acc_half8(float* __restrict__ acc, const __half* __restrict__ p) {
    uint4 u = *(const uint4*)p;
    const __half2* h = (const __half2*)&u;
    float2 f0 = __half22float2(h[0]);
    float2 f1 = __half22float2(h[1]);
    float2 f2 = __half22float2(h[2]);
    float2 f3 = __half22float2(h[3]);
    acc[0] += f0.x; acc[1] += f0.y; acc[2] += f1.x; acc[3] += f1.y;
    acc[4] += f2.x; acc[5] += f2.y; acc[6] += f3.x; acc[7] += f3.y;
}

// ---- aggregation KOUT=128 (fp16 rows, 256B): quarter-wave per row ->
// 4 edges per load instruction. fp32 accumulate. ----
template <bool RELU>
__global__ __launch_bounds__(256) void agg128(const __half* __restrict__ Ys,
                                              const int* __restrict__ rowptr,
                                              const int* __restrict__ deg,
                                              const float* __restrict__ dinv,
                                              const int* __restrict__ colidx,
                                              const float* __restrict__ bias,
                                              float* __restrict__ out, int n) {
    int wid = (blockIdx.x * blockDim.x + threadIdx.x) >> 6;
    int lane = threadIdx.x & 63;
    if (wid >= n) return;
    const int q = lane >> 4;     // edge slot within a quad of edges
    const int l4 = lane & 15;    // col chunk: halves l4*8 .. l4*8+7

    int start = __builtin_amdgcn_readfirstlane(rowptr[wid]);
    int dg    = __builtin_amdgcn_readfirstlane(deg[wid]);
    int mpad  = padcap(dg);
    float di = dinv[wid];

    float acc[8];
#pragma unroll
    for (int j = 0; j < 8; j++) acc[j] = 0.f;
    if (q == 0) acc_half8(acc, Ys + ((size_t)wid << 7) + l4 * 8);  // self term

    const int4* cp4 = (const int4*)(colidx + start);   // start % 8 == 0
    for (int j = 0; j < mpad; j += 8) {
        int4 a = cp4[j >> 2];
        int4 b = cp4[(j >> 2) + 1];
        int s0 = sel4(a, q);
        int s1 = sel4(b, q);
        acc_half8(acc, Ys + ((size_t)s0 << 7) + l4 * 8);
        acc_half8(acc, Ys + ((size_t)s1 << 7) + l4 * 8);
    }
    // combine the 4 quads
#pragma unroll
    for (int j = 0; j < 8; j++) {
        acc[j] += __shfl_xor(acc[j], 16);
        acc[j] += __shfl_xor(acc[j], 32);
    }

    if (q == 0) {
        float scale = di / (float)dg;
        float4 b0 = *(const float4*)(bias + l4 * 8);
        float4 b1 = *(const float4*)(bias + l4 * 8 + 4);
        float o[8];
        o[0] = acc[0] * scale + b0.x; o[1] = acc[1] * scale + b0.y;
        o[2] = acc[2] * scale + b0.z; o[3] = acc[3] * scale + b0.w;
        o[4] = acc[4] * scale + b1.x; o[5] = acc[5] * scale + b1.y;
        o[6] = acc[6] * scale + b1.z; o[7] = acc[7] * scale + b1.w;
        if (RELU) {
#pragma unroll
            for (int j = 0; j < 8; j++) o[j] = fmaxf(o[j], 0.f);
        }
        float* op = out + ((size_t)wid << 7) + l4 * 8;
        *(float4*)op = make_float4(o[0], o[1], o[2], o[3]);
        *(float4*)(op + 4) = make_float4(o[4], o[5], o[6], o[7]);
    }
}

// ---- aggregation KOUT=64 (fp16 rows, 128B): eighth-wave per row ->
// 8 edges per load instruction. ----
template <bool RELU>
__global__ __launch_bounds__(256) void agg64(const __half* __restrict__ Ys,
                                             const int* __restrict__ rowptr,
                                             const int* __restrict__ deg,
                                             const float* __restrict__ dinv,
                                             const int* __restrict__ colidx,
                                             const float* __restrict__ bias,
                                             float* __restrict__ out, int n) {
    int wid = (blockIdx.x * blockDim.x + threadIdx.x) >> 6;
    int lane = threadIdx.x & 63;
    if (wid >= n) return;
    const int oct = lane >> 3;   // edge slot within an octet of edges
    const int l3 = lane & 7;     // col chunk: halves l3*8 .. l3*8+7

    int start = __builtin_amdgcn_readfirstlane(rowptr[wid]);
    int dg    = __builtin_amdgcn_readfirstlane(deg[wid]);
    int mpad  = padcap(dg);
    float di = dinv[wid];

    float acc[8];
#pragma unroll
    for (int j = 0; j < 8; j++) acc[j] = 0.f;
    if (oct == 0) acc_half8(acc, Ys + ((size_t)wid << 6) + l3 * 8);  // self term

    const int4* cp4 = (const int4*)(colidx + start);
    for (int j = 0; j < mpad; j += 8) {
        int4 a = cp4[j >> 2];
        int4 b = cp4[(j >> 2) + 1];
        int se = (oct < 4) ? sel4(a, oct) : sel4(b, oct - 4);
        acc_half8(acc, Ys + ((size_t)se << 6) + l3 * 8);
    }
    // combine the 8 octets
#pragma unroll
    for (int j = 0; j < 8; j++) {
        acc[j] += __shfl_xor(acc[j], 8);
        acc[j] += __shfl_xor(acc[j], 16);
        acc[j] += __shfl_xor(acc[j], 32);
    }

    if (oct == 0) {
        float scale = di / (float)dg;
        float4 b0 = *(const float4*)(bias + l3 * 8);
        float4 b1 = *(const float4*)(bias + l3 * 8 + 4);
        float o[8];
        o[0] = acc[0] * scale + b0.x; o[1] = acc[1] * scale + b0.y;
        o[2] = acc[2] * scale + b0.z; o[3] = acc[3] * scale + b0.w;
        o[4] = acc[4] * scale + b1.x; o[5] = acc[5] * scale + b1.y;
        o[6] = acc[6] * scale + b1.z; o[7] = acc[7] * scale + b1.w;
        if (RELU) {
#pragma unroll
            for (int j = 0; j < 8; j++) o[j] = fmaxf(o[j], 0.f);
        }
        float* op = out + ((size_t)wid << 6) + l3 * 8;
        *(float4*)op = make_float4(o[0], o[1], o[2], o[3]);
        *(float4*)(op + 4) = make_float4(o[4], o[5], o[6], o[7]);
    }
}

extern "C" void kernel_launch(void* const* d_in, const int* in_sizes, int n_in,
                              void* d_out, int out_size, void* d_ws, size_t ws_size,
                              hipStream_t stream) {
    const float* x  = (const float*)d_in[0];
    const int*   ei = (const int*)d_in[1];
    const float* W1 = (const float*)d_in[2];
    const float* b1 = (const float*)d_in[3];
    const float* W2 = (const float*)d_in[4];
    const float* b2 = (const float*)d_in[5];
    const float* W3 = (const float*)d_in[6];
    const float* b3 = (const float*)d_in[7];
    float* out = (float*)d_out;

    const int n = in_sizes[0] / 128;      // 100000
    const int E = in_sizes[1] / 2;        // 1600000
    const int* srcA = ei;
    const int* dstA = ei + E;
    const int Epad = E + 8 * n + 64;      // CSR padded to 8 per node + slack

    // ---- workspace carve (aligned to 256B) ----
    auto alignup = [](size_t v) { return (v + 255) & ~(size_t)255; };
    char* base = (char*)d_ws;
    size_t off = 0;
    int* deg    = (int*)(base + off); off = alignup(off + (size_t)n * 4);
    int* fill   = (int*)(base + off); off = alignup(off + (size_t)n * 4);
    int* rowptr = (int*)(base + off); off = alignup(off + (size_t)n * 4);
    int* bsum   = (int*)(base + off); off = alignup(off + (size_t)1024 * 4);
    int* colidx = (int*)(base + off); off = alignup(off + (size_t)Epad * 4);
    float* dinv = (float*)(base + off); off = alignup(off + (size_t)n * 4);
    float* Hb   = (float*)(base + off); off = alignup(off + (size_t)n * 128 * 4);
    __half* Yb  = (__half*)(base + off); off = alignup(off + (size_t)(n + 1) * 128 * 2);
    (void)ws_size;

    const int nbN = (n + BLK - 1) / BLK;      // 391
    const int nbE = (E + BLK - 1) / BLK;

    // ---- prep: degrees, dinv, padded CSR (holes -> zero-row index n) ----
    init_and_pad<<<2048, BLK, 0, stream>>>(deg, fill, n, colidx, n, Epad);
    count_deg<<<nbE, BLK, 0, stream>>>(dstA, deg, E);
    scan_block_sums<<<nbN, BLK, 0, stream>>>(deg, bsum, n);
    scan_partials_excl<<<1, 512, 0, stream>>>(bsum, nbN);
    scan_write_rowptr<<<nbN, BLK, 0, stream>>>(deg, bsum, rowptr, dinv, n);
    place_edges<<<nbE, BLK, 0, stream>>>(srcA, dstA, rowptr, fill, colidx, E);

    const int aggBlocks = (n * 64 + BLK - 1) / BLK;   // wave per node

    // ---- layer 1: x @ W1 -> agg -> relu -> Hb ----
    gemm_tiled<128><<<(n + 63) / 64, 256, 0, stream>>>(x, W1, dinv, Yb, n);
    agg128<true><<<aggBlocks, BLK, 0, stream>>>(Yb, rowptr, deg, dinv, colidx, b1, Hb, n);

    // ---- layer 2 ----
    gemm_tiled<128><<<(n + 63) / 64, 256, 0, stream>>>(Hb, W2, dinv, Yb, n);
    agg128<true><<<aggBlocks, BLK, 0, stream>>>(Yb, rowptr, deg, dinv, colidx, b2, Hb, n);

    // ---- layer 3 (out dim 64, no relu) ----
    gemm_tiled<64><<<(n + 127) / 128, 256, 0, stream>>>(Hb, W3, dinv, Yb, n);
    agg64<false><<<aggBlocks, BLK, 0, stream>>>(Yb, rowptr, deg, dinv, colidx, b3, out, n);
}

// Round 7
// 409.047 us; speedup vs baseline: 1.6055x; 1.1983x over previous
//
#include <hip/hip_runtime.h>
#include <hip/hip_fp16.h>
#include <math.h>

// ---------------------------------------------------------------------------
// GCN 3-layer forward, fp32 compute, fp16 gather payload.
//  per layer: Ys = fp16( dinv .* (H @ W) ) ;  out_i = dinv_i*( Ys_i +
//             sum_e Ys[src_e] ) / deg_i + b   (accumulated in fp32)
// CSR-by-dst built on device each call; segments padded to multiples of 8,
// holes point at zero-row index n (Ys has n+1 rows, row n = 0).
// R2: LDS-tiled register-blocked GEMM (no spills).
// R4: shfl-free aggregation, dinv folded into Y at GEMM epilogue, padded CSR.
// R6: fp16 Y payload (halves structural 8-XCD L2 refill traffic).
// R7: rank trick — count_deg's atomicAdd return IS the edge's slot rank;
//     place_edges becomes atomic-free (dependent atomic->scatter chain was
//     111us, pure write-line-bound scatter should be ~35us).
// ---------------------------------------------------------------------------

#define BLK 256

// init deg=1 and colidx=zero-row over padded length (grid-stride)
__global__ void init_and_pad(int* __restrict__ deg, int n,
                             int* __restrict__ colidx, int val, int len) {
    int i = blockIdx.x * blockDim.x + threadIdx.x;
    int stride = gridDim.x * blockDim.x;
    for (; i < len; i += stride) {
        if (i < n) deg[i] = 1;
        colidx[i] = val;
    }
}

// count in-degree AND record each edge's arrival rank (atomic return value)
__global__ void count_deg_rank(const int* __restrict__ dst, int* __restrict__ deg,
                               int* __restrict__ rank, int E) {
    int e = blockIdx.x * blockDim.x + threadIdx.x;
    if (e < E) {
        int old = atomicAdd(&deg[dst[e]], 1);   // deg starts at 1 (self-loop)
        rank[e] = old - 1;                      // 0-based slot within segment
    }
}

// padded per-node edge capacity: roundup8(deg-1)
__device__ __forceinline__ int padcap(int d) { return (d - 1 + 7) & ~7; }

// ---- exclusive scan of padcap(deg) into rowptr, 3 passes ----
__global__ void scan_block_sums(const int* __restrict__ deg, int* __restrict__ bsum, int n) {
    __shared__ int s[BLK];
    int i = blockIdx.x * BLK + threadIdx.x;
    s[threadIdx.x] = (i < n) ? padcap(deg[i]) : 0;
    __syncthreads();
    for (int off = BLK / 2; off > 0; off >>= 1) {
        if (threadIdx.x < off) s[threadIdx.x] += s[threadIdx.x + off];
        __syncthreads();
    }
    if (threadIdx.x == 0) bsum[blockIdx.x] = s[0];
}

__global__ void scan_partials_excl(int* __restrict__ bsum, int nb) {
    __shared__ int a[512];
    __shared__ int b[512];
    int t = threadIdx.x;
    int v = (t < nb) ? bsum[t] : 0;
    a[t] = v;
    __syncthreads();
    int* s = a; int* d = b;
    for (int off = 1; off < 512; off <<= 1) {
        int val = s[t];
        if (t >= off) val += s[t - off];
        d[t] = val;
        __syncthreads();
        int* tmp = s; s = d; d = tmp;
    }
    if (t < nb) bsum[t] = s[t] - v;   // exclusive
}

__global__ void scan_write_rowptr(const int* __restrict__ deg, const int* __restrict__ bsum,
                                  int* __restrict__ rowptr, float* __restrict__ dinv, int n) {
    __shared__ int a[BLK];
    __shared__ int b[BLK];
    int t = threadIdx.x;
    int i = blockIdx.x * BLK + t;
    int dgv = (i < n) ? deg[i] : 1;
    int v = (i < n) ? padcap(dgv) : 0;
    a[t] = v;
    __syncthreads();
    int* s = a; int* d = b;
    for (int off = 1; off < BLK; off <<= 1) {
        int val = s[t];
        if (t >= off) val += s[t - off];
        d[t] = val;
        __syncthreads();
        int* tmp = s; s = d; d = tmp;
    }
    if (i < n) {
        rowptr[i] = (s[t] - v) + bsum[blockIdx.x];
        dinv[i] = 1.0f / sqrtf((float)dgv);
    }
}

// atomic-free placement: slot = rowptr[dst] + rank (rank from count pass)
__global__ void place_edges(const int* __restrict__ src, const int* __restrict__ dst,
                            const int* __restrict__ rowptr, const int* __restrict__ rank,
                            int* __restrict__ colidx, int E) {
    int e = blockIdx.x * blockDim.x + threadIdx.x;
    if (e < E) {
        int d = dst[e];
        colidx[rowptr[d] + rank[e]] = src[e];
    }
}

// ---- GEMM: Ys[n+1,KOUT] fp16; rows<n: fp16(dinv[row]*(H@W)); row n: zeros ----
template <int KOUT>
__global__ __launch_bounds__(256) void gemm_tiled(const float* __restrict__ H,
                                                  const float* __restrict__ W,
                                                  const float* __restrict__ dinv,
                                                  __half* __restrict__ Y, int n) {
    constexpr int ROWS = (KOUT == 128) ? 64 : 128;
    constexpr int HSTR = 36;  // padded k-stride: float4 aligned, conflict-free reads
    __shared__ float Hl[ROWS][HSTR];   // [row][kk]
    __shared__ float Wl[32][KOUT];     // [kk][c]

    const int t = threadIdx.x;
    const int wave = t >> 6, lane = t & 63;
    const int rg = lane >> 3;          // 0..7 row group
    const int cg = lane & 7;           // 0..7 col group
    const int rpanel = (KOUT == 128) ? (wave >> 1) : wave;
    const int cpanel = (KOUT == 128) ? (wave & 1) : 0;
    const int row0 = blockIdx.x * ROWS;
    const int cbase = cpanel * 64 + cg * 8;

    if (blockIdx.x == 0 && t < KOUT) Y[(size_t)n * KOUT + t] = __float2half(0.f);

    float acc[4][8];
#pragma unroll
    for (int i = 0; i < 4; i++)
#pragma unroll
        for (int j = 0; j < 8; j++) acc[i][j] = 0.f;

    for (int kt = 0; kt < 128; kt += 32) {
        // stage H tile: ROWS x 32 (8 threads/row, float4 each; coalesced 128B/row)
#pragma unroll
        for (int s = 0; s < ROWS / 32; s++) {
            int r = s * 32 + (t >> 3);
            int kk = (t & 7) * 4;
            int row = row0 + r;
            float4 v = make_float4(0.f, 0.f, 0.f, 0.f);
            if (row < n) v = *(const float4*)(H + (size_t)row * 128 + kt + kk);
            Hl[r][kk] = v.x; Hl[r][kk + 1] = v.y; Hl[r][kk + 2] = v.z; Hl[r][kk + 3] = v.w;
        }
        // stage W tile: 32 x KOUT, contiguous chunk
        {
            const float* Wg = W + (size_t)kt * KOUT;
            float* Wf = &Wl[0][0];
            for (int idx = t * 4; idx < 32 * KOUT; idx += 1024) {
                *(float4*)(Wf + idx) = *(const float4*)(Wg + idx);
            }
        }
        __syncthreads();

#pragma unroll 2
        for (int kk = 0; kk < 32; kk += 4) {
            float4 a[4];
#pragma unroll
            for (int i = 0; i < 4; i++)
                a[i] = *(const float4*)(&Hl[rpanel * 32 + rg + 8 * i][kk]);
#pragma unroll
            for (int q = 0; q < 4; q++) {
                float4 w0 = *(const float4*)(&Wl[kk + q][cbase]);
                float4 w1 = *(const float4*)(&Wl[kk + q][cbase + 4]);
#pragma unroll
                for (int i = 0; i < 4; i++) {
                    float av = (q == 0) ? a[i].x : (q == 1) ? a[i].y : (q == 2) ? a[i].z : a[i].w;
                    acc[i][0] += av * w0.x; acc[i][1] += av * w0.y;
                    acc[i][2] += av * w0.z; acc[i][3] += av * w0.w;
                    acc[i][4] += av * w1.x; acc[i][5] += av * w1.y;
                    acc[i][6] += av * w1.z; acc[i][7] += av * w1.w;
                }
            }
        }
        __syncthreads();
    }

#pragma unroll
    for (int i = 0; i < 4; i++) {
        int row = row0 + rpanel * 32 + rg + 8 * i;
        if (row < n) {
            float dv = dinv[row];
            __half hv[8];
#pragma unroll
            for (int j = 0; j < 8; j++) hv[j] = __float2half_rn(dv * acc[i][j]);
            *(uint4*)(Y + (size_t)row * KOUT + cbase) = *(const uint4*)hv;
        }
    }
}

__device__ __forceinline__ int sel4(const int4 v, int q) {
    return (q == 0) ? v.x : (q == 1) ? v.y : (q == 2) ? v.z : v.w;
}

__device__ __forceinline__ void acc_half8(float* __restrict__ acc, const __half* __restrict__ p) {
    uint4 u = *(const uint4*)p;
    const __half2* h = (const __half2*)&u;
    float2 f0 = __half22float2(h[0]);
    float2 f1 = __half22float2(h[1]);
    float2 f2 = __half22float2(h[2]);
    float2 f3 = __half22float2(h[3]);
    acc[0] += f0.x; acc[1] += f0.y; acc[2] += f1.x; acc[3] += f1.y;
    acc[4] += f2.x; acc[5] += f2.y; acc[6] += f3.x; acc[7] += f3.y;
}

// ---- aggregation KOUT=128 (fp16 rows, 256B): quarter-wave per row ->
// 4 edges per load instruction. fp32 accumulate. ----
template <bool RELU>
__global__ __launch_bounds__(256) void agg128(const __half* __restrict__ Ys,
                                              const int* __restrict__ rowptr,
                                              const int* __restrict__ deg,
                                              const float* __restrict__ dinv,
                                              const int* __restrict__ colidx,
                                              const float* __restrict__ bias,
                                              float* __restrict__ out, int n) {
    int wid = (blockIdx.x * blockDim.x + threadIdx.x) >> 6;
    int lane = threadIdx.x & 63;
    if (wid >= n) return;
    const int q = lane >> 4;     // edge slot within a quad of edges
    const int l4 = lane & 15;    // col chunk: halves l4*8 .. l4*8+7

    int start = __builtin_amdgcn_readfirstlane(rowptr[wid]);
    int dg    = __builtin_amdgcn_readfirstlane(deg[wid]);
    int mpad  = padcap(dg);
    float di = dinv[wid];

    float acc[8];
#pragma unroll
    for (int j = 0; j < 8; j++) acc[j] = 0.f;
    if (q == 0) acc_half8(acc, Ys + ((size_t)wid << 7) + l4 * 8);  // self term

    const int4* cp4 = (const int4*)(colidx + start);   // start % 8 == 0
    for (int j = 0; j < mpad; j += 8) {
        int4 a = cp4[j >> 2];
        int4 b = cp4[(j >> 2) + 1];
        int s0 = sel4(a, q);
        int s1 = sel4(b, q);
        acc_half8(acc, Ys + ((size_t)s0 << 7) + l4 * 8);
        acc_half8(acc, Ys + ((size_t)s1 << 7) + l4 * 8);
    }
    // combine the 4 quads
#pragma unroll
    for (int j = 0; j < 8; j++) {
        acc[j] += __shfl_xor(acc[j], 16);
        acc[j] += __shfl_xor(acc[j], 32);
    }

    if (q == 0) {
        float scale = di / (float)dg;
        float4 b0 = *(const float4*)(bias + l4 * 8);
        float4 b1 = *(const float4*)(bias + l4 * 8 + 4);
        float o[8];
        o[0] = acc[0] * scale + b0.x; o[1] = acc[1] * scale + b0.y;
        o[2] = acc[2] * scale + b0.z; o[3] = acc[3] * scale + b0.w;
        o[4] = acc[4] * scale + b1.x; o[5] = acc[5] * scale + b1.y;
        o[6] = acc[6] * scale + b1.z; o[7] = acc[7] * scale + b1.w;
        if (RELU) {
#pragma unroll
            for (int j = 0; j < 8; j++) o[j] = fmaxf(o[j], 0.f);
        }
        float* op = out + ((size_t)wid << 7) + l4 * 8;
        *(float4*)op = make_float4(o[0], o[1], o[2], o[3]);
        *(float4*)(op + 4) = make_float4(o[4], o[5], o[6], o[7]);
    }
}

// ---- aggregation KOUT=64 (fp16 rows, 128B): eighth-wave per row ->
// 8 edges per load instruction. ----
template <bool RELU>
__global__ __launch_bounds__(256) void agg64(const __half* __restrict__ Ys,
                                             const int* __restrict__ rowptr,
                                             const int* __restrict__ deg,
                                             const float* __restrict__ dinv,
                                             const int* __restrict__ colidx,
                                             const float* __restrict__ bias,
                                             float* __restrict__ out, int n) {
    int wid = (blockIdx.x * blockDim.x + threadIdx.x) >> 6;
    int lane = threadIdx.x & 63;
    if (wid >= n) return;
    const int oct = lane >> 3;   // edge slot within an octet of edges
    const int l3 = lane & 7;     // col chunk: halves l3*8 .. l3*8+7

    int start = __builtin_amdgcn_readfirstlane(rowptr[wid]);
    int dg    = __builtin_amdgcn_readfirstlane(deg[wid]);
    int mpad  = padcap(dg);
    float di = dinv[wid];

    float acc[8];
#pragma unroll
    for (int j = 0; j < 8; j++) acc[j] = 0.f;
    if (oct == 0) acc_half8(acc, Ys + ((size_t)wid << 6) + l3 * 8);  // self term

    const int4* cp4 = (const int4*)(colidx + start);
    for (int j = 0; j < mpad; j += 8) {
        int4 a = cp4[j >> 2];
        int4 b = cp4[(j >> 2) + 1];
        int se = (oct < 4) ? sel4(a, oct) : sel4(b, oct - 4);
        acc_half8(acc, Ys + ((size_t)se << 6) + l3 * 8);
    }
    // combine the 8 octets
#pragma unroll
    for (int j = 0; j < 8; j++) {
        acc[j] += __shfl_xor(acc[j], 8);
        acc[j] += __shfl_xor(acc[j], 16);
        acc[j] += __shfl_xor(acc[j], 32);
    }

    if (oct == 0) {
        float scale = di / (float)dg;
        float4 b0 = *(const float4*)(bias + l3 * 8);
        float4 b1 = *(const float4*)(bias + l3 * 8 + 4);
        float o[8];
        o[0] = acc[0] * scale + b0.x; o[1] = acc[1] * scale + b0.y;
        o[2] = acc[2] * scale + b0.z; o[3] = acc[3] * scale + b0.w;
        o[4] = acc[4] * scale + b1.x; o[5] = acc[5] * scale + b1.y;
        o[6] = acc[6] * scale + b1.z; o[7] = acc[7] * scale + b1.w;
        if (RELU) {
#pragma unroll
            for (int j = 0; j < 8; j++) o[j] = fmaxf(o[j], 0.f);
        }
        float* op = out + ((size_t)wid << 6) + l3 * 8;
        *(float4*)op = make_float4(o[0], o[1], o[2], o[3]);
        *(float4*)(op + 4) = make_float4(o[4], o[5], o[6], o[7]);
    }
}

extern "C" void kernel_launch(void* const* d_in, const int* in_sizes, int n_in,
                              void* d_out, int out_size, void* d_ws, size_t ws_size,
                              hipStream_t stream) {
    const float* x  = (const float*)d_in[0];
    const int*   ei = (const int*)d_in[1];
    const float* W1 = (const float*)d_in[2];
    const float* b1 = (const float*)d_in[3];
    const float* W2 = (const float*)d_in[4];
    const float* b2 = (const float*)d_in[5];
    const float* W3 = (const float*)d_in[6];
    const float* b3 = (const float*)d_in[7];
    float* out = (float*)d_out;

    const int n = in_sizes[0] / 128;      // 100000
    const int E = in_sizes[1] / 2;        // 1600000
    const int* srcA = ei;
    const int* dstA = ei + E;
    const int Epad = E + 8 * n + 64;      // CSR padded to 8 per node + slack

    // ---- workspace carve (aligned to 256B) ----
    auto alignup = [](size_t v) { return (v + 255) & ~(size_t)255; };
    char* base = (char*)d_ws;
    size_t off = 0;
    int* deg    = (int*)(base + off); off = alignup(off + (size_t)n * 4);
    int* rank   = (int*)(base + off); off = alignup(off + (size_t)E * 4);
    int* rowptr = (int*)(base + off); off = alignup(off + (size_t)n * 4);
    int* bsum   = (int*)(base + off); off = alignup(off + (size_t)1024 * 4);
    int* colidx = (int*)(base + off); off = alignup(off + (size_t)Epad * 4);
    float* dinv = (float*)(base + off); off = alignup(off + (size_t)n * 4);
    float* Hb   = (float*)(base + off); off = alignup(off + (size_t)n * 128 * 4);
    __half* Yb  = (__half*)(base + off); off = alignup(off + (size_t)(n + 1) * 128 * 2);
    (void)ws_size;

    const int nbN = (n + BLK - 1) / BLK;      // 391
    const int nbE = (E + BLK - 1) / BLK;

    // ---- prep: degrees+ranks, dinv, padded CSR (holes -> zero-row index n) ----
    init_and_pad<<<2048, BLK, 0, stream>>>(deg, n, colidx, n, Epad);
    count_deg_rank<<<nbE, BLK, 0, stream>>>(dstA, deg, rank, E);
    scan_block_sums<<<nbN, BLK, 0, stream>>>(deg, bsum, n);
    scan_partials_excl<<<1, 512, 0, stream>>>(bsum, nbN);
    scan_write_rowptr<<<nbN, BLK, 0, stream>>>(deg, bsum, rowptr, dinv, n);
    place_edges<<<nbE, BLK, 0, stream>>>(srcA, dstA, rowptr, rank, colidx, E);

    const int aggBlocks = (n * 64 + BLK - 1) / BLK;   // wave per node

    // ---- layer 1: x @ W1 -> agg -> relu -> Hb ----
    gemm_tiled<128><<<(n + 63) / 64, 256, 0, stream>>>(x, W1, dinv, Yb, n);
    agg128<true><<<aggBlocks, BLK, 0, stream>>>(Yb, rowptr, deg, dinv, colidx, b1, Hb, n);

    // ---- layer 2 ----
    gemm_tiled<128><<<(n + 63) / 64, 256, 0, stream>>>(Hb, W2, dinv, Yb, n);
    agg128<true><<<aggBlocks, BLK, 0, stream>>>(Yb, rowptr, deg, dinv, colidx, b2, Hb, n);

    // ---- layer 3 (out dim 64, no relu) ----
    gemm_tiled<64><<<(n + 127) / 128, 256, 0, stream>>>(Hb, W3, dinv, Yb, n);
    agg64<false><<<aggBlocks, BLK, 0, stream>>>(Yb, rowptr, deg, dinv, colidx, b3, out, n);
}

// Round 8
// 345.423 us; speedup vs baseline: 1.9012x; 1.1842x over previous
//
#include <hip/hip_runtime.h>
#include <hip/hip_fp16.h>
#include <math.h>

// ---------------------------------------------------------------------------
// GCN 3-layer forward. bf16 MFMA GEMM, fp16 gather payload, fp32 accumulate.
//  per layer: Ys = fp16( dinv .* (H @ W) ) ;  out_i = dinv_i*( Ys_i +
//             sum_e Ys[src_e] ) / deg_i + b
// CSR-by-dst built on device each call; segments padded to multiples of 8,
// holes point at zero-row index n (Ys has n+1 rows, row n = 0).
// R4: shfl-free agg, dinv folded into Y epilogue, padded CSR.
// R6: fp16 Y payload (structural 8-XCD x |Y| L2 refill floor ~3.4 TB/s).
// R7: rank trick - atomic-free place_edges.
// R8: (a) MFMA bf16 GEMM (W pre-transposed+cast to bf16 [n][k]; whole K=128
//     in LDS; fp32 GEMM was 52% of 157TF vector peak, MFMA makes it mem-bound)
//     (b) agg128 emits bf16 H directly (halves inter-layer H traffic, feeds
//     next GEMM without cast)  (c) 4-way edge MLP in count/place kernels.
// ---------------------------------------------------------------------------

#define BLK 256

typedef short bf16x8 __attribute__((ext_vector_type(8)));
typedef float f32x4 __attribute__((ext_vector_type(4)));

__device__ __forceinline__ unsigned short f2bf(float f) {
    unsigned int u = __float_as_uint(f);
    u += 0x7fffu + ((u >> 16) & 1u);        // round-to-nearest-even
    return (unsigned short)(u >> 16);
}

// init deg=1 and colidx=zero-row over padded length (grid-stride)
__global__ void init_and_pad(int* __restrict__ deg, int n,
                             int* __restrict__ colidx, int val, int len) {
    int i = blockIdx.x * blockDim.x + threadIdx.x;
    int stride = gridDim.x * blockDim.x;
    for (; i < len; i += stride) {
        if (i < n) deg[i] = 1;
        colidx[i] = val;
    }
}

// one-shot: W[k][n] fp32 -> Wt[n][k] bf16, all three layers
__global__ void transpose_cast_w3(const float* __restrict__ W1, const float* __restrict__ W2,
                                  const float* __restrict__ W3, unsigned short* __restrict__ Wt1,
                                  unsigned short* __restrict__ Wt2, unsigned short* __restrict__ Wt3) {
    int idx = blockIdx.x * blockDim.x + threadIdx.x;
    if (idx < 16384) {
        int k = idx >> 7, c = idx & 127;
        Wt1[c * 128 + k] = f2bf(W1[idx]);
    } else if (idx < 32768) {
        int j = idx - 16384; int k = j >> 7, c = j & 127;
        Wt2[c * 128 + k] = f2bf(W2[j]);
    } else if (idx < 40960) {
        int j = idx - 32768; int k = j >> 6, c = j & 63;
        Wt3[c * 128 + k] = f2bf(W3[j]);
    }
}

// count in-degree AND record each edge's arrival rank; 4 edges per thread
// (independent atomics in flight — the single-atomic version was latency-bound)
__global__ void count_deg_rank(const int* __restrict__ dst, int* __restrict__ deg,
                               int* __restrict__ rank, int E) {
    int t = blockIdx.x * blockDim.x + threadIdx.x;
    int s = gridDim.x * blockDim.x;
    int e0 = t, e1 = t + s, e2 = t + 2 * s, e3 = t + 3 * s;
    int d0 = 0, d1 = 0, d2 = 0, d3 = 0;
    if (e0 < E) d0 = dst[e0];
    if (e1 < E) d1 = dst[e1];
    if (e2 < E) d2 = dst[e2];
    if (e3 < E) d3 = dst[e3];
    int r0 = 0, r1 = 0, r2 = 0, r3 = 0;
    if (e0 < E) r0 = atomicAdd(&deg[d0], 1);
    if (e1 < E) r1 = atomicAdd(&deg[d1], 1);
    if (e2 < E) r2 = atomicAdd(&deg[d2], 1);
    if (e3 < E) r3 = atomicAdd(&deg[d3], 1);
    if (e0 < E) rank[e0] = r0 - 1;
    if (e1 < E) rank[e1] = r1 - 1;
    if (e2 < E) rank[e2] = r2 - 1;
    if (e3 < E) rank[e3] = r3 - 1;
}

// padded per-node edge capacity: roundup8(deg-1)
__device__ __forceinline__ int padcap(int d) { return (d - 1 + 7) & ~7; }

// ---- exclusive scan of padcap(deg) into rowptr, 3 passes ----
__global__ void scan_block_sums(const int* __restrict__ deg, int* __restrict__ bsum, int n) {
    __shared__ int s[BLK];
    int i = blockIdx.x * BLK + threadIdx.x;
    s[threadIdx.x] = (i < n) ? padcap(deg[i]) : 0;
    __syncthreads();
    for (int off = BLK / 2; off > 0; off >>= 1) {
        if (threadIdx.x < off) s[threadIdx.x] += s[threadIdx.x + off];
        __syncthreads();
    }
    if (threadIdx.x == 0) bsum[blockIdx.x] = s[0];
}

__global__ void scan_partials_excl(int* __restrict__ bsum, int nb) {
    __shared__ int a[512];
    __shared__ int b[512];
    int t = threadIdx.x;
    int v = (t < nb) ? bsum[t] : 0;
    a[t] = v;
    __syncthreads();
    int* s = a; int* d = b;
    for (int off = 1; off < 512; off <<= 1) {
        int val = s[t];
        if (t >= off) val += s[t - off];
        d[t] = val;
        __syncthreads();
        int* tmp = s; s = d; d = tmp;
    }
    if (t < nb) bsum[t] = s[t] - v;   // exclusive
}

__global__ void scan_write_rowptr(const int* __restrict__ deg, const int* __restrict__ bsum,
                                  int* __restrict__ rowptr, float* __restrict__ dinv, int n) {
    __shared__ int a[BLK];
    __shared__ int b[BLK];
    int t = threadIdx.x;
    int i = blockIdx.x * BLK + t;
    int dgv = (i < n) ? deg[i] : 1;
    int v = (i < n) ? padcap(dgv) : 0;
    a[t] = v;
    __syncthreads();
    int* s = a; int* d = b;
    for (int off = 1; off < BLK; off <<= 1) {
        int val = s[t];
        if (t >= off) val += s[t - off];
        d[t] = val;
        __syncthreads();
        int* tmp = s; s = d; d = tmp;
    }
    if (i < n) {
        rowptr[i] = (s[t] - v) + bsum[blockIdx.x];
        dinv[i] = 1.0f / sqrtf((float)dgv);
    }
}

// atomic-free placement, 4 edges per thread
__global__ void place_edges(const int* __restrict__ src, const int* __restrict__ dst,
                            const int* __restrict__ rowptr, const int* __restrict__ rank,
                            int* __restrict__ colidx, int E) {
    int t = blockIdx.x * blockDim.x + threadIdx.x;
    int s = gridDim.x * blockDim.x;
    int e0 = t, e1 = t + s, e2 = t + 2 * s, e3 = t + 3 * s;
    int d0 = 0, d1 = 0, d2 = 0, d3 = 0;
    if (e0 < E) d0 = dst[e0];
    if (e1 < E) d1 = dst[e1];
    if (e2 < E) d2 = dst[e2];
    if (e3 < E) d3 = dst[e3];
    int p0 = 0, p1 = 0, p2 = 0, p3 = 0;
    if (e0 < E) p0 = rowptr[d0] + rank[e0];
    if (e1 < E) p1 = rowptr[d1] + rank[e1];
    if (e2 < E) p2 = rowptr[d2] + rank[e2];
    if (e3 < E) p3 = rowptr[d3] + rank[e3];
    if (e0 < E) colidx[p0] = src[e0];
    if (e1 < E) colidx[p1] = src[e1];
    if (e2 < E) colidx[p2] = src[e2];
    if (e3 < E) colidx[p3] = src[e3];
}

// ---- MFMA GEMM: Ys[n+1,KOUT] fp16 = fp16(dinv .* (H @ W)); row n zeros ----
// Block: 64 rows x KOUT cols, 4 waves (wave = 16 rows), whole K=128 in LDS.
// A-frag: H[row=lane&15][k=(lane>>4)*8+i]; B-frag: Wt[col=lane&15][same k];
// C/D: col=lane&15, row=(lane>>4)*4+reg (guide-verified layout).
template <int KOUT, bool INF32>
__global__ __launch_bounds__(256) void gemm_mfma(const void* __restrict__ Hv,
                                                 const unsigned short* __restrict__ Wt,
                                                 const float* __restrict__ dinv,
                                                 __half* __restrict__ Y, int n) {
    constexpr int NCH = KOUT / 16;
    __shared__ unsigned short Hl[64][136];     // [row][k], +8 pad: 2-way banks max
    __shared__ unsigned short Wl[KOUT][136];   // [col][k]
    const int t = threadIdx.x;
    const int row0 = blockIdx.x * 64;

    // stage Wt (bf16 [KOUT][128] global, coalesced 16B chunks)
    for (int idx = t; idx < KOUT * 16; idx += 256) {
        int r = idx >> 4, seg = idx & 15;
        *(uint4*)&Wl[r][seg * 8] = *(const uint4*)(Wt + r * 128 + seg * 8);
    }
    // stage H tile (64 rows x 128 k), cast fp32->bf16 if layer 1
    if (INF32) {
        const float* H = (const float*)Hv;
        for (int idx = t; idx < 64 * 16; idx += 256) {
            int r = idx >> 4, seg = idx & 15;
            int row = row0 + r;
            unsigned short tmp[8];
            if (row < n) {
                float4 v0 = *(const float4*)(H + (size_t)row * 128 + seg * 8);
                float4 v1 = *(const float4*)(H + (size_t)row * 128 + seg * 8 + 4);
                tmp[0] = f2bf(v0.x); tmp[1] = f2bf(v0.y); tmp[2] = f2bf(v0.z); tmp[3] = f2bf(v0.w);
                tmp[4] = f2bf(v1.x); tmp[5] = f2bf(v1.y); tmp[6] = f2bf(v1.z); tmp[7] = f2bf(v1.w);
            } else {
#pragma unroll
                for (int j = 0; j < 8; j++) tmp[j] = 0;
            }
            *(uint4*)&Hl[r][seg * 8] = *(const uint4*)tmp;
        }
    } else {
        const unsigned short* H = (const unsigned short*)Hv;
        for (int idx = t; idx < 64 * 16; idx += 256) {
            int r = idx >> 4, seg = idx & 15;
            int row = row0 + r;
            uint4 v = make_uint4(0, 0, 0, 0);
            if (row < n) v = *(const uint4*)(H + (size_t)row * 128 + seg * 8);
            *(uint4*)&Hl[r][seg * 8] = v;
        }
    }
    if (blockIdx.x == 0 && t < KOUT) Y[(size_t)n * KOUT + t] = __float2half(0.f);
    __syncthreads();

    const int wave = t >> 6, lane = t & 63;
    const int r16 = lane & 15, ko8 = (lane >> 4) * 8;
    f32x4 acc[NCH];
#pragma unroll
    for (int c = 0; c < NCH; c++) acc[c] = (f32x4){0.f, 0.f, 0.f, 0.f};

#pragma unroll
    for (int kc = 0; kc < 4; kc++) {
        bf16x8 a = *(const bf16x8*)&Hl[wave * 16 + r16][kc * 32 + ko8];
#pragma unroll
        for (int c = 0; c < NCH; c++) {
            bf16x8 b = *(const bf16x8*)&Wl[c * 16 + r16][kc * 32 + ko8];
            acc[c] = __builtin_amdgcn_mfma_f32_16x16x32_bf16(a, b, acc[c], 0, 0, 0);
        }
    }

    const int mbase = row0 + wave * 16 + (lane >> 4) * 4;
#pragma unroll
    for (int r = 0; r < 4; r++) {
        int row = mbase + r;
        if (row < n) {
            float dv = dinv[row];
#pragma unroll
            for (int c = 0; c < NCH; c++)
                Y[(size_t)row * KOUT + c * 16 + r16] = __float2half_rn(acc[c][r] * dv);
        }
    }
}

__device__ __forceinline__ int sel4(const int4 v, int q) {
    return (q == 0) ? v.x : (q == 1) ? v.y : (q == 2) ? v.z : v.w;
}

__device__ __forceinline__ void acc_half8(float* __restrict__ acc, const __half* __restrict__ p) {
    uint4 u = *(const uint4*)p;
    const __half2* h = (const __half2*)&u;
    float2 f0 = __half22float2(h[0]);
    float2 f1 = __half22float2(h[1]);
    float2 f2 = __half22float2(h[2]);
    float2 f3 = __half22float2(h[3]);
    acc[0] += f0.x; acc[1] += f0.y; acc[2] += f1.x; acc[3] += f1.y;
    acc[4] += f2.x; acc[5] += f2.y; acc[6] += f3.x; acc[7] += f3.y;
}

// ---- aggregation KOUT=128: quarter-wave per row, 4 edges/load-inst;
// relu applied; emits bf16 H rows (next GEMM's input). ----
__global__ __launch_bounds__(256) void agg128(const __half* __restrict__ Ys,
                                              const int* __restrict__ rowptr,
                                              const int* __restrict__ deg,
                                              const float* __restrict__ dinv,
                                              const int* __restrict__ colidx,
                                              const float* __restrict__ bias,
                                              unsigned short* __restrict__ outb, int n) {
    int wid = (blockIdx.x * blockDim.x + threadIdx.x) >> 6;
    int lane = threadIdx.x & 63;
    if (wid >= n) return;
    const int q = lane >> 4;     // edge slot within a quad of edges
    const int l4 = lane & 15;    // col chunk: halves l4*8 .. l4*8+7

    int start = __builtin_amdgcn_readfirstlane(rowptr[wid]);
    int dg    = __builtin_amdgcn_readfirstlane(deg[wid]);
    int mpad  = padcap(dg);
    float di = dinv[wid];

    float acc[8];
#pragma unroll
    for (int j = 0; j < 8; j++) acc[j] = 0.f;
    if (q == 0) acc_half8(acc, Ys + ((size_t)wid << 7) + l4 * 8);  // self term

    const int4* cp4 = (const int4*)(colidx + start);   // start % 8 == 0
    for (int j = 0; j < mpad; j += 8) {
        int4 a = cp4[j >> 2];
        int4 b = cp4[(j >> 2) + 1];
        int s0 = sel4(a, q);
        int s1 = sel4(b, q);
        acc_half8(acc, Ys + ((size_t)s0 << 7) + l4 * 8);
        acc_half8(acc, Ys + ((size_t)s1 << 7) + l4 * 8);
    }
#pragma unroll
    for (int j = 0; j < 8; j++) {
        acc[j] += __shfl_xor(acc[j], 16);
        acc[j] += __shfl_xor(acc[j], 32);
    }

    if (q == 0) {
        float scale = di / (float)dg;
        float4 b0 = *(const float4*)(bias + l4 * 8);
        float4 b1 = *(const float4*)(bias + l4 * 8 + 4);
        unsigned short ob[8];
        ob[0] = f2bf(fmaxf(acc[0] * scale + b0.x, 0.f));
        ob[1] = f2bf(fmaxf(acc[1] * scale + b0.y, 0.f));
        ob[2] = f2bf(fmaxf(acc[2] * scale + b0.z, 0.f));
        ob[3] = f2bf(fmaxf(acc[3] * scale + b0.w, 0.f));
        ob[4] = f2bf(fmaxf(acc[4] * scale + b1.x, 0.f));
        ob[5] = f2bf(fmaxf(acc[5] * scale + b1.y, 0.f));
        ob[6] = f2bf(fmaxf(acc[6] * scale + b1.z, 0.f));
        ob[7] = f2bf(fmaxf(acc[7] * scale + b1.w, 0.f));
        *(uint4*)(outb + ((size_t)wid << 7) + l4 * 8) = *(const uint4*)ob;
    }
}

// ---- aggregation KOUT=64: eighth-wave per row, 8 edges/load-inst; fp32 out ----
__global__ __launch_bounds__(256) void agg64(const __half* __restrict__ Ys,
                                             const int* __restrict__ rowptr,
                                             const int* __restrict__ deg,
                                             const float* __restrict__ dinv,
                                             const int* __restrict__ colidx,
                                             const float* __restrict__ bias,
                                             float* __restrict__ out, int n) {
    int wid = (blockIdx.x * blockDim.x + threadIdx.x) >> 6;
    int lane = threadIdx.x & 63;
    if (wid >= n) return;
    const int oct = lane >> 3;   // edge slot within an octet of edges
    const int l3 = lane & 7;     // col chunk: halves l3*8 .. l3*8+7

    int start = __builtin_amdgcn_readfirstlane(rowptr[wid]);
    int dg    = __builtin_amdgcn_readfirstlane(deg[wid]);
    int mpad  = padcap(dg);
    float di = dinv[wid];

    float acc[8];
#pragma unroll
    for (int j = 0; j < 8; j++) acc[j] = 0.f;
    if (oct == 0) acc_half8(acc, Ys + ((size_t)wid << 6) + l3 * 8);  // self term

    const int4* cp4 = (const int4*)(colidx + start);
    for (int j = 0; j < mpad; j += 8) {
        int4 a = cp4[j >> 2];
        int4 b = cp4[(j >> 2) + 1];
        int se = (oct < 4) ? sel4(a, oct) : sel4(b, oct - 4);
        acc_half8(acc, Ys + ((size_t)se << 6) + l3 * 8);
    }
#pragma unroll
    for (int j = 0; j < 8; j++) {
        acc[j] += __shfl_xor(acc[j], 8);
        acc[j] += __shfl_xor(acc[j], 16);
        acc[j] += __shfl_xor(acc[j], 32);
    }

    if (oct == 0) {
        float scale = di / (float)dg;
        float4 b0 = *(const float4*)(bias + l3 * 8);
        float4 b1 = *(const float4*)(bias + l3 * 8 + 4);
        float o[8];
        o[0] = acc[0] * scale + b0.x; o[1] = acc[1] * scale + b0.y;
        o[2] = acc[2] * scale + b0.z; o[3] = acc[3] * scale + b0.w;
        o[4] = acc[4] * scale + b1.x; o[5] = acc[5] * scale + b1.y;
        o[6] = acc[6] * scale + b1.z; o[7] = acc[7] * scale + b1.w;
        float* op = out + ((size_t)wid << 6) + l3 * 8;
        *(float4*)op = make_float4(o[0], o[1], o[2], o[3]);
        *(float4*)(op + 4) = make_float4(o[4], o[5], o[6], o[7]);
    }
}

extern "C" void kernel_launch(void* const* d_in, const int* in_sizes, int n_in,
                              void* d_out, int out_size, void* d_ws, size_t ws_size,
                              hipStream_t stream) {
    const float* x  = (const float*)d_in[0];
    const int*   ei = (const int*)d_in[1];
    const float* W1 = (const float*)d_in[2];
    const float* b1 = (const float*)d_in[3];
    const float* W2 = (const float*)d_in[4];
    const float* b2 = (const float*)d_in[5];
    const float* W3 = (const float*)d_in[6];
    const float* b3 = (const float*)d_in[7];
    float* out = (float*)d_out;

    const int n = in_sizes[0] / 128;      // 100000
    const int E = in_sizes[1] / 2;        // 1600000
    const int* srcA = ei;
    const int* dstA = ei + E;
    const int Epad = E + 8 * n + 64;      // CSR padded to 8 per node + slack

    // ---- workspace carve (aligned to 256B) ----
    auto alignup = [](size_t v) { return (v + 255) & ~(size_t)255; };
    char* base = (char*)d_ws;
    size_t off = 0;
    int* deg    = (int*)(base + off); off = alignup(off + (size_t)n * 4);
    int* rank   = (int*)(base + off); off = alignup(off + (size_t)E * 4);
    int* rowptr = (int*)(base + off); off = alignup(off + (size_t)n * 4);
    int* bsum   = (int*)(base + off); off = alignup(off + (size_t)1024 * 4);
    int* colidx = (int*)(base + off); off = alignup(off + (size_t)Epad * 4);
    float* dinv = (float*)(base + off); off = alignup(off + (size_t)n * 4);
    unsigned short* Wt1 = (unsigned short*)(base + off); off = alignup(off + 16384 * 2);
    unsigned short* Wt2 = (unsigned short*)(base + off); off = alignup(off + 16384 * 2);
    unsigned short* Wt3 = (unsigned short*)(base + off); off = alignup(off + 8192 * 2);
    unsigned short* Hb  = (unsigned short*)(base + off); off = alignup(off + (size_t)n * 128 * 2);
    __half* Yb  = (__half*)(base + off); off = alignup(off + (size_t)(n + 1) * 128 * 2);
    (void)ws_size;

    const int nbN = (n + BLK - 1) / BLK;          // 391
    const int nbE4 = (E + BLK * 4 - 1) / (BLK * 4);

    // ---- prep: W transpose+cast, degrees+ranks, dinv, padded CSR ----
    init_and_pad<<<2048, BLK, 0, stream>>>(deg, n, colidx, n, Epad);
    transpose_cast_w3<<<160, BLK, 0, stream>>>(W1, W2, W3, Wt1, Wt2, Wt3);
    count_deg_rank<<<nbE4, BLK, 0, stream>>>(dstA, deg, rank, E);
    scan_block_sums<<<nbN, BLK, 0, stream>>>(deg, bsum, n);
    scan_partials_excl<<<1, 512, 0, stream>>>(bsum, nbN);
    scan_write_rowptr<<<nbN, BLK, 0, stream>>>(deg, bsum, rowptr, dinv, n);
    place_edges<<<nbE4, BLK, 0, stream>>>(srcA, dstA, rowptr, rank, colidx, E);

    const int aggBlocks = (n * 64 + BLK - 1) / BLK;   // wave per node
    const int gemmBlocks = (n + 63) / 64;             // 1563

    // ---- layer 1: x @ W1 -> agg+relu -> Hb (bf16) ----
    gemm_mfma<128, true><<<gemmBlocks, 256, 0, stream>>>(x, Wt1, dinv, Yb, n);
    agg128<<<aggBlocks, BLK, 0, stream>>>(Yb, rowptr, deg, dinv, colidx, b1, Hb, n);

    // ---- layer 2 ----
    gemm_mfma<128, false><<<gemmBlocks, 256, 0, stream>>>(Hb, Wt2, dinv, Yb, n);
    agg128<<<aggBlocks, BLK, 0, stream>>>(Yb, rowptr, deg, dinv, colidx, b2, Hb, n);

    // ---- layer 3 (out dim 64, no relu, fp32 out) ----
    gemm_mfma<64, false><<<gemmBlocks, 256, 0, stream>>>(Hb, Wt3, dinv, Yb, n);
    agg64<<<aggBlocks, BLK, 0, stream>>>(Yb, rowptr, deg, dinv, colidx, b3, out, n);
}